// Round 8
// baseline (250.098 us; speedup 1.0000x reference)
//
#include <hip/hip_runtime.h>
#include <math.h>

typedef __attribute__((ext_vector_type(8))) short bf16x8;
typedef __attribute__((ext_vector_type(4))) float f32x4;
typedef __attribute__((ext_vector_type(4))) int i32x4;

typedef __attribute__((address_space(3))) void lds_void;
typedef __attribute__((address_space(1))) const void glb_cvoid;

__device__ __forceinline__ unsigned short f32_to_bf16(float f) {
    unsigned u = __float_as_uint(f);
    unsigned r = (u + 0x7FFFu + ((u >> 16) & 1u)) >> 16;
    return (unsigned short)r;
}
__device__ __forceinline__ float bf16_to_f32(unsigned short h) {
    return __uint_as_float(((unsigned)h) << 16);
}

// ---------------------------------------------------------------------------
// f32 -> bf16 hi (+ optional lo residual) converter. n4 = n/4 float4 groups.
// ---------------------------------------------------------------------------
__global__ __launch_bounds__(256)
void split_bf16(const float* __restrict__ src, unsigned short* __restrict__ hi,
                unsigned short* __restrict__ lo, int n4)
{
    const int i = blockIdx.x * 256 + threadIdx.x;
    if (i >= n4) return;
    float4 v = *reinterpret_cast<const float4*>(src + (size_t)i * 4);
    ushort4 h;
    h.x = f32_to_bf16(v.x); h.y = f32_to_bf16(v.y);
    h.z = f32_to_bf16(v.z); h.w = f32_to_bf16(v.w);
    *reinterpret_cast<ushort4*>(hi + (size_t)i * 4) = h;
    if (lo) {
        ushort4 l;
        l.x = f32_to_bf16(v.x - bf16_to_f32(h.x));
        l.y = f32_to_bf16(v.y - bf16_to_f32(h.y));
        l.z = f32_to_bf16(v.z - bf16_to_f32(h.z));
        l.w = f32_to_bf16(v.w - bf16_to_f32(h.w));
        *reinterpret_cast<ushort4*>(lo + (size_t)i * 4) = l;
    }
}

// Split of the four 256x1024 freq/phase weights (one launch):
//   WfH/WfL = [WqfH;WkfH]/[lo]  (512x1024, split)
//   WpH     = [WqpH;WkpH]       (512x1024, hi only — phase needs no residual)
__global__ __launch_bounds__(256)
void split4_bf16(const float* __restrict__ Wqf, const float* __restrict__ Wkf,
                 const float* __restrict__ Wqp, const float* __restrict__ Wkp,
                 unsigned short* __restrict__ WfH, unsigned short* __restrict__ WfL,
                 unsigned short* __restrict__ WpH)
{
    const int i = blockIdx.x * 256 + threadIdx.x;   // 0..262143 (float4 units)
    const int sel = i >> 16, j = i & 65535;
    const float* W = (sel == 0) ? Wqf : (sel == 1) ? Wkf : (sel == 2) ? Wqp : Wkp;
    float4 v = *reinterpret_cast<const float4*>(W + (size_t)j * 4);
    ushort4 h;
    h.x = f32_to_bf16(v.x); h.y = f32_to_bf16(v.y);
    h.z = f32_to_bf16(v.z); h.w = f32_to_bf16(v.w);
    const size_t o = (size_t)(sel & 1) * 262144 + (size_t)j * 4;
    if (sel < 2) {
        *reinterpret_cast<ushort4*>(WfH + o) = h;
        ushort4 l;
        l.x = f32_to_bf16(v.x - bf16_to_f32(h.x));
        l.y = f32_to_bf16(v.y - bf16_to_f32(h.y));
        l.z = f32_to_bf16(v.z - bf16_to_f32(h.z));
        l.w = f32_to_bf16(v.w - bf16_to_f32(h.w));
        *reinterpret_cast<ushort4*>(WfL + o) = l;
    } else {
        *reinterpret_cast<ushort4*>(WpH + o) = h;
    }
}

// XCD-aware bijective remap: all bn-tiles of an A-panel share one XCD
// (hw xcd ~ linear_id % 8).  Requires nbm % 8 == 0.
__device__ __forceinline__ void xcd_tiles(int& tm, int& tn) {
    const int L = blockIdx.x + gridDim.x * blockIdx.y;
    const int nbn = gridDim.x;
    const int q3 = L >> 3;
    tn = q3 % nbn;
    tm = (L & 7) + 8 * (q3 / nbn);
}

// fast sin: v_sin_f32 takes revolutions (period 1). arg error ~2e-4 rad at
// |x|~2500 — well inside the bf16 phase-noise budget (~1e-3).
__device__ __forceinline__ float fast_sin(float x) {
    float r = x * 0.15915494309189535f;
    return __sinf(r * 6.2831853071795865f) * 0.f + __sinf(x);  // placeholder-free: use __sinf directly
}

// ---------------------------------------------------------------------------
// Fused freq+phase projection GEMM + sin + l2norm -> qn/kn bf16 [b,h,t,w].
// Tile 64(M:t) x 64(N:col), BK=64, 256 thr = 4 waves (2x2), wave owns 32x32.
// 2-PHASE PIPELINE (T3/T4): double-buffered LDS, prefetch t+1 before compute
// of t, counted s_waitcnt vmcnt(4) (never 0 mid-loop), raw s_barrier.
// K-segments: 0: xh*WfH, 1: xl*WfH, 2: xh*WfL  -> accF (split precision)
//             3: xh*WpH                        -> accP (plain bf16)
// ---------------------------------------------------------------------------
__global__ __launch_bounds__(256)
void freq_gemm_norm(const unsigned short* __restrict__ xh,
                    const unsigned short* __restrict__ xl,
                    const unsigned short* __restrict__ WfH,
                    const unsigned short* __restrict__ WfL,
                    const unsigned short* __restrict__ WpH,
                    const float* __restrict__ bqf, const float* __restrict__ bkf,
                    const float* __restrict__ bqp, const float* __restrict__ bkp,
                    unsigned short* __restrict__ qn, unsigned short* __restrict__ kn)
{
    __shared__ __attribute__((aligned(16))) unsigned short Al[2 * 64 * 64];
    __shared__ __attribute__((aligned(16))) unsigned short Bl[2 * 64 * 64];

    int tm, tn;
    xcd_tiles(tm, tn);                 // nbm=64, nbn=8
    const int bm = tm * 64, bn = tn * 64;

    const int tid = threadIdx.x;
    const int w = tid >> 6, l = tid & 63;
    const int wr = w >> 1, wc = w & 1;
    const int lr = l & 15, lg = l >> 4;
    const int r8 = l >> 3;             // staging row in 8-row chunk
    const int c8 = l & 7;              // 16B slot in 128B row
    const int csw = (c8 ^ r8) << 3;    // inverse-swizzled global col

    f32x4 accF[2][2], accP[2][2];
#pragma unroll
    for (int i = 0; i < 2; i++)
#pragma unroll
        for (int j = 0; j < 2; j++)
#pragma unroll
            for (int r = 0; r < 4; r++) { accF[i][j][r] = 0.f; accP[i][j][r] = 0.f; }

    auto stage = [&](int t, int buf) {
        const int seg = t >> 4;
        const int kc = (t << 6) & 1023;
        const unsigned short* Aseg = (seg == 1) ? xl : xh;
        const unsigned short* Bseg = (seg <= 1) ? WfH : (seg == 2) ? WfL : WpH;
        unsigned short* Ad = Al + buf * 4096;
        unsigned short* Bd = Bl + buf * 4096;
#pragma unroll
        for (int i = 0; i < 2; i++) {
            __builtin_amdgcn_global_load_lds(
                (glb_cvoid*)(Aseg + (size_t)(bm + w * 16 + i * 8 + r8) * 1024 + kc + csw),
                (lds_void*)(&Ad[(w * 16 + i * 8) * 64]), 16, 0, 0);
            __builtin_amdgcn_global_load_lds(
                (glb_cvoid*)(Bseg + (size_t)(bn + w * 16 + i * 8 + r8) * 1024 + kc + csw),
                (lds_void*)(&Bd[(w * 16 + i * 8) * 64]), 16, 0, 0);
        }
    };

    stage(0, 0);
    for (int t = 0; t < 64; ++t) {
        const int cur = t & 1;
        if (t < 63) {
            stage(t + 1, cur ^ 1);
            asm volatile("s_waitcnt vmcnt(4)" ::: "memory");
        } else {
            asm volatile("s_waitcnt vmcnt(0)" ::: "memory");
        }
        __builtin_amdgcn_s_barrier();
        asm volatile("" ::: "memory");

        const unsigned short* Ac = Al + cur * 4096;
        const unsigned short* Bc = Bl + cur * 4096;
        bf16x8 af[2][2], bfr[2][2];
#pragma unroll
        for (int i = 0; i < 2; i++)
#pragma unroll
            for (int kk = 0; kk < 2; kk++) {
                af[i][kk] = *reinterpret_cast<const bf16x8*>(
                    &Ac[(wr * 32 + i * 16 + lr) * 64 + (((kk * 4 + lg) ^ (lr & 7)) << 3)]);
                bfr[i][kk] = *reinterpret_cast<const bf16x8*>(
                    &Bc[(wc * 32 + i * 16 + lr) * 64 + (((kk * 4 + lg) ^ (lr & 7)) << 3)]);
            }
        if ((t >> 4) < 3) {
#pragma unroll
            for (int kk = 0; kk < 2; kk++)
#pragma unroll
                for (int i = 0; i < 2; i++)
#pragma unroll
                    for (int j = 0; j < 2; j++)
                        accF[i][j] = __builtin_amdgcn_mfma_f32_16x16x32_bf16(
                            af[i][kk], bfr[j][kk], accF[i][j], 0, 0, 0);
        } else {
#pragma unroll
            for (int kk = 0; kk < 2; kk++)
#pragma unroll
                for (int i = 0; i < 2; i++)
#pragma unroll
                    for (int j = 0; j < 2; j++)
                        accP[i][j] = __builtin_amdgcn_mfma_f32_16x16x32_bf16(
                            af[i][kk], bfr[j][kk], accP[i][j], 0, 0, 0);
        }
        __builtin_amdgcn_s_barrier();
        asm volatile("" ::: "memory");
    }

    // epilogue: C/D col = lane&15, row = lg*4 + reg
#pragma unroll
    for (int i = 0; i < 2; i++) {
#pragma unroll
        for (int j = 0; j < 2; j++) {
            const int col = bn + wc * 32 + j * 16 + lr;   // 0..511
            const bool isQ = col < 256;
            const int c = col & 255;
            const float bf = isQ ? bqf[c] : bkf[c];
            const float bp = isQ ? bqp[c] : bkp[c];
            unsigned short* dst = isQ ? qn : kn;
            const int h = c >> 4, ww = c & 15;
#pragma unroll
            for (int r = 0; r < 4; r++) {
                const int row = bm + wr * 32 + i * 16 + lg * 4 + r;
                const int b = row >> 10, t = row & 1023;
                const float f = accF[i][j][r] + bf;
                const float p = accP[i][j][r] + bp;
                const float s = __sinf(fmaf(f, (float)t, p));
                float n2 = s * s;
#pragma unroll
                for (int off = 8; off >= 1; off >>= 1)
                    n2 += __shfl_xor(n2, off);
                const float val = s * 2.0f / fmaxf(sqrtf(n2), 1e-12f);
                dst[((size_t)(b * 16 + h) * 1024 + t) * 16 + ww] = f32_to_bf16(val);
            }
        }
    }
}

// ---------------------------------------------------------------------------
// bf16 MFMA GEMM, 2-phase pipelined: C[m,n] = sum_k A[m,k]*B[n,k].
// Tile 128(M) x 64(N), BK=64, 256 threads = 4 waves (2x2), each wave 64x32.
// Double-buffered LDS + counted vmcnt(6) + raw barriers (T3/T4 minimum).
// MODE 1 (v):    K=1024, +bias, writes vtt[b,h,d,t] bf16 (d-major!).
// MODE 2 (out):  K=1024, +bias, writes f32 (d_out).
// ---------------------------------------------------------------------------
template <int MODE>
__global__ __launch_bounds__(256)
void mfma_gemm(const unsigned short* __restrict__ A0,
               const unsigned short* __restrict__ B0,
               const float* __restrict__ bias,
               float* __restrict__ outF, unsigned short* __restrict__ outH)
{
    __shared__ __attribute__((aligned(16))) unsigned short Al[2 * 128 * 64];
    __shared__ __attribute__((aligned(16))) unsigned short Bl[2 * 64 * 64];

    int tm, tn;
    xcd_tiles(tm, tn);                 // nbm=32, nbn=gridDim.x
    const int bm = tm * 128, bn = tn * 64;

    const int tid = threadIdx.x;
    const int w = tid >> 6, l = tid & 63;
    const int wr = w >> 1, wc = w & 1;
    const int lr = l & 15, lg = l >> 4;
    const int r8 = l >> 3;
    const int c8 = l & 7;
    const int csw = (c8 ^ r8) << 3;

    f32x4 acc[4][2];
#pragma unroll
    for (int i = 0; i < 4; i++)
#pragma unroll
        for (int j = 0; j < 2; j++)
#pragma unroll
            for (int r = 0; r < 4; r++) acc[i][j][r] = 0.f;

    auto stage = [&](int t, int buf) {
        const int k0 = t << 6;
        unsigned short* Ad = Al + buf * 8192;
        unsigned short* Bd = Bl + buf * 4096;
#pragma unroll
        for (int i = 0; i < 4; i++)
            __builtin_amdgcn_global_load_lds(
                (glb_cvoid*)(A0 + (size_t)(bm + w * 32 + i * 8 + r8) * 1024 + k0 + csw),
                (lds_void*)(&Ad[(w * 32 + i * 8) * 64]), 16, 0, 0);
#pragma unroll
        for (int i = 0; i < 2; i++)
            __builtin_amdgcn_global_load_lds(
                (glb_cvoid*)(B0 + (size_t)(bn + w * 16 + i * 8 + r8) * 1024 + k0 + csw),
                (lds_void*)(&Bd[(w * 16 + i * 8) * 64]), 16, 0, 0);
    };

    stage(0, 0);
    for (int t = 0; t < 16; ++t) {
        const int cur = t & 1;
        if (t < 15) {
            stage(t + 1, cur ^ 1);
            asm volatile("s_waitcnt vmcnt(6)" ::: "memory");
        } else {
            asm volatile("s_waitcnt vmcnt(0)" ::: "memory");
        }
        __builtin_amdgcn_s_barrier();
        asm volatile("" ::: "memory");

        const unsigned short* Ac = Al + cur * 8192;
        const unsigned short* Bc = Bl + cur * 4096;
        bf16x8 af[4][2], bfr[2][2];
#pragma unroll
        for (int i = 0; i < 4; i++)
#pragma unroll
            for (int kk = 0; kk < 2; kk++)
                af[i][kk] = *reinterpret_cast<const bf16x8*>(
                    &Ac[(wr * 64 + i * 16 + lr) * 64 + (((kk * 4 + lg) ^ (lr & 7)) << 3)]);
#pragma unroll
        for (int j = 0; j < 2; j++)
#pragma unroll
            for (int kk = 0; kk < 2; kk++)
                bfr[j][kk] = *reinterpret_cast<const bf16x8*>(
                    &Bc[(wc * 32 + j * 16 + lr) * 64 + (((kk * 4 + lg) ^ (lr & 7)) << 3)]);
#pragma unroll
        for (int kk = 0; kk < 2; kk++)
#pragma unroll
            for (int i = 0; i < 4; i++)
#pragma unroll
                for (int j = 0; j < 2; j++)
                    acc[i][j] = __builtin_amdgcn_mfma_f32_16x16x32_bf16(
                        af[i][kk], bfr[j][kk], acc[i][j], 0, 0, 0);
        __builtin_amdgcn_s_barrier();
        asm volatile("" ::: "memory");
    }

#pragma unroll
    for (int i = 0; i < 4; i++) {
#pragma unroll
        for (int j = 0; j < 2; j++) {
#pragma unroll
            for (int r = 0; r < 4; r++) {
                const int row = bm + wr * 64 + i * 16 + lg * 4 + r;
                const int col = bn + wc * 32 + j * 16 + lr;
                float v = acc[i][j][r] + bias[col];
                if (MODE == 1) {
                    const int hh = col >> 6, d = col & 63;
                    const int b = row >> 10, t = row & 1023;
                    outH[(((size_t)(b * 16 + hh) * 64 + d) * 1024) + t] =
                        f32_to_bf16(v);
                } else {
                    outF[(size_t)row * 1024 + col] = v;
                }
            }
        }
    }
}

// ---------------------------------------------------------------------------
// MFMA causal linear attention, pair-balanced (unchanged from round 6/7).
// grid (8, bh=64), 512 thr = 8 independent waves (no LDS, no barriers).
// ---------------------------------------------------------------------------
__global__ __launch_bounds__(512)
void wave_attn_mfma(const unsigned short* __restrict__ qn,
                    const unsigned short* __restrict__ kn,
                    const unsigned short* __restrict__ vtt,
                    const float* __restrict__ iscale,
                    unsigned short* __restrict__ y)
{
    const int p = blockIdx.x, bh = blockIdx.y;
    const int h = bh & 15, b = bh >> 4;
    const int tid = threadIdx.x;
    const int wq = tid >> 6;          // wave 0..7
    const int l = tid & 63;
    const int lt = l & 15;
    const int gl = l >> 4;
    const int it = (wq < 4) ? p : (15 - p);
    const int t0w = it * 64 + (wq & 3) * 16;
    const float scale = iscale[h];
    const int tmine = t0w + lt;

    const bf16x8 zero8 = {0, 0, 0, 0, 0, 0, 0, 0};
    const f32x4 zf = {0.f, 0.f, 0.f, 0.f};
    const size_t kb = (size_t)bh * 1024;

    bf16x8 bq = zero8;
    if (gl < 2)
        bq = *reinterpret_cast<const bf16x8*>(&qn[(kb + t0w + lt) * 16 + gl * 8]);

    f32x4 o[4];
#pragma unroll
    for (int jd = 0; jd < 4; jd++) o[jd] = zf;

    const int addr0 = ((2 * (gl & 1)) * 16 + lt) * 4;
    const int addr1 = addr0 + 64;
    const bool hi = ((gl >> 1) & 1) != 0;

    bf16x8 akc[4], akn[4];
#pragma unroll
    for (int js = 0; js < 4; js++) {
        akc[js] = zero8;
        if (gl < 2)
            akc[js] = *reinterpret_cast<const bf16x8*>(
                &kn[(kb + js * 16 + lt) * 16 + gl * 8]);
    }

    for (int is = 0; is <= it; is++) {
        const int s0 = is * 64;

        if (is < it) {
#pragma unroll
            for (int js = 0; js < 4; js++) {
                akn[js] = zero8;
                if (gl < 2)
                    akn[js] = *reinterpret_cast<const bf16x8*>(
                        &kn[(kb + s0 + 64 + js * 16 + lt) * 16 + gl * 8]);
            }
        }
        bf16x8 bv[2][4];
#pragma unroll
        for (int ks = 0; ks < 2; ks++)
#pragma unroll
            for (int jd = 0; jd < 4; jd++)
                bv[ks][jd] = *reinterpret_cast<const bf16x8*>(
                    &vtt[((size_t)(bh * 64 + jd * 16 + lt)) * 1024 +
                         s0 + ks * 32 + gl * 8]);

        f32x4 st[4];
#pragma unroll
        for (int js = 0; js < 4; js++)
            st[js] = __builtin_amdgcn_mfma_f32_16x16x32_bf16(
                akc[js], bq, zf, 0, 0, 0);

        int pk[4][2];
#pragma unroll
        for (int js = 0; js < 4; js++) {
            float pp[4];
#pragma unroll
            for (int r = 0; r < 4; r++) {
                const int s = s0 + js * 16 + gl * 4 + r;
                const float xv = st[js][r] * scale;
                const float phi = (xv > 0.f) ? (xv + 1.0f) : __expf(xv);
                pp[r] = (s <= tmine) ? phi : 0.f;
            }
            asm("v_cvt_pk_bf16_f32 %0, %1, %2"
                : "=v"(pk[js][0]) : "v"(pp[0]), "v"(pp[1]));
            asm("v_cvt_pk_bf16_f32 %0, %1, %2"
                : "=v"(pk[js][1]) : "v"(pp[2]), "v"(pp[3]));
        }

        int rg[4][2][2];
#pragma unroll
        for (int js = 0; js < 4; js++)
#pragma unroll
            for (int sl = 0; sl < 2; sl++) {
                rg[js][sl][0] = __builtin_amdgcn_ds_bpermute(addr0, pk[js][sl]);
                rg[js][sl][1] = __builtin_amdgcn_ds_bpermute(addr1, pk[js][sl]);
            }

#pragma unroll
        for (int ks = 0; ks < 2; ks++) {
            i32x4 au;
#pragma unroll
            for (int c = 0; c < 2; c++)
#pragma unroll
                for (int sl = 0; sl < 2; sl++)
                    au[2 * c + sl] = hi ? rg[2 * ks + 1][sl][c]
                                        : rg[2 * ks][sl][c];
            const bf16x8 pa = __builtin_bit_cast(bf16x8, au);
#pragma unroll
            for (int jd = 0; jd < 4; jd++)
                o[jd] = __builtin_amdgcn_mfma_f32_16x16x32_bf16(
                    pa, bv[ks][jd], o[jd], 0, 0, 0);
        }

#pragma unroll
        for (int js = 0; js < 4; js++) akc[js] = akn[js];
    }

#pragma unroll
    for (int r = 0; r < 4; r++) {
        const int t = t0w + gl * 4 + r;
        const float inv = rsqrtf((float)(t + 1));
#pragma unroll
        for (int jd = 0; jd < 4; jd++) {
            const int d = jd * 16 + lt;
            y[((size_t)b * 1024 + t) * 1024 + h * 64 + d] =
                f32_to_bf16(o[jd][r] * inv);
        }
    }
}

// ---------------------------------------------------------------------------
extern "C" void kernel_launch(void* const* d_in, const int* in_sizes, int n_in,
                              void* d_out, int out_size, void* d_ws, size_t ws_size,
                              hipStream_t stream)
{
    const float* x   = (const float*)d_in[0];
    const float* Wqf = (const float*)d_in[1];
    const float* bqf = (const float*)d_in[2];
    const float* Wkf = (const float*)d_in[3];
    const float* bkf = (const float*)d_in[4];
    const float* Wqp = (const float*)d_in[5];
    const float* bqp = (const float*)d_in[6];
    const float* Wkp = (const float*)d_in[7];
    const float* bkp = (const float*)d_in[8];
    const float* Wv  = (const float*)d_in[9];
    const float* bv  = (const float*)d_in[10];
    const float* Wo  = (const float*)d_in[11];
    const float* bo  = (const float*)d_in[12];
    const float* isc = (const float*)d_in[13];
    float* out = (float*)d_out;

    // workspace plan (34 MB, zero live-range overlaps):
    //   [ 0, 8) ybf bf16 (attn out)
    //   [ 8,10) qn bf16   [10,12) kn bf16
    //   [12,13) WfH       [13,14) WfL       [14,15) WpH   (512x1024 each)
    //   [16,24) xh bf16   (dead after v GEMM)
    //   [24,32) xl bf16 -> vtt bf16 [b,h,d,t] after fused freq GEMM
    //   [32,34) WvH -> WoH (2 MB)
    char* ws = (char*)d_ws;
    unsigned short* ybf = (unsigned short*)(ws);
    unsigned short* qn  = (unsigned short*)(ws + ( 8u << 20));
    unsigned short* kn  = (unsigned short*)(ws + (10u << 20));
    unsigned short* WfH = (unsigned short*)(ws + (12u << 20));
    unsigned short* WfL = (unsigned short*)(ws + (13u << 20));
    unsigned short* WpH = (unsigned short*)(ws + (14u << 20));
    unsigned short* xh  = (unsigned short*)(ws + (16u << 20));
    unsigned short* xl  = (unsigned short*)(ws + (24u << 20));
    unsigned short* vtt = (unsigned short*)(ws + (24u << 20));
    unsigned short* WvH = (unsigned short*)(ws + (32u << 20));
    unsigned short* WoH = WvH;   // slot reuse after v GEMM

    // conversions
    split_bf16<<<4096, 256, 0, stream>>>(x, xh, xl, 1048576);
    split4_bf16<<<1024, 256, 0, stream>>>(Wqf, Wkf, Wqp, Wkp, WfH, WfL, WpH);

    // 1) fused freq(split K=3072) + phase(K=1024) GEMM + sin + l2norm
    freq_gemm_norm<<<dim3(8, 64), 256, 0, stream>>>(
        xh, xl, WfH, WfL, WpH, bqf, bkf, bqp, bkp, qn, kn);

    // 2) v projection -> vtt bf16 [b,h,d,t]  (overlays dead xl)
    split_bf16<<<1024, 256, 0, stream>>>(Wv, WvH, nullptr, 262144);
    mfma_gemm<1><<<dim3(16, 32), 256, 0, stream>>>(xh, WvH, bv, nullptr, vtt);

    // 3) MFMA causal linear attention (pair-balanced) -> ybf bf16
    wave_attn_mfma<<<dim3(8, 64), 512, 0, stream>>>(qn, kn, vtt, isc, ybf);

    // 4) output projection -> d_out f32
    split_bf16<<<1024, 256, 0, stream>>>(Wo, WoH, nullptr, 262144);
    mfma_gemm<2><<<dim3(16, 32), 256, 0, stream>>>(ybf, WoH, bo, out, nullptr);
}

// Round 9
// 220.268 us; speedup vs baseline: 1.1354x; 1.1354x over previous
//
#include <hip/hip_runtime.h>
#include <math.h>

typedef __attribute__((ext_vector_type(8))) short bf16x8;
typedef __attribute__((ext_vector_type(4))) float f32x4;
typedef __attribute__((ext_vector_type(4))) int i32x4;

typedef __attribute__((address_space(3))) void lds_void;
typedef __attribute__((address_space(1))) const void glb_cvoid;

__device__ __forceinline__ unsigned short f32_to_bf16(float f) {
    unsigned u = __float_as_uint(f);
    unsigned r = (u + 0x7FFFu + ((u >> 16) & 1u)) >> 16;
    return (unsigned short)r;
}
__device__ __forceinline__ float bf16_to_f32(unsigned short h) {
    return __uint_as_float(((unsigned)h) << 16);
}

// ---------------------------------------------------------------------------
// f32 -> bf16 hi (+ optional lo residual) converter. n4 = n/4 float4 groups.
// ---------------------------------------------------------------------------
__global__ __launch_bounds__(256)
void split_bf16(const float* __restrict__ src, unsigned short* __restrict__ hi,
                unsigned short* __restrict__ lo, int n4)
{
    const int i = blockIdx.x * 256 + threadIdx.x;
    if (i >= n4) return;
    float4 v = *reinterpret_cast<const float4*>(src + (size_t)i * 4);
    ushort4 h;
    h.x = f32_to_bf16(v.x); h.y = f32_to_bf16(v.y);
    h.z = f32_to_bf16(v.z); h.w = f32_to_bf16(v.w);
    *reinterpret_cast<ushort4*>(hi + (size_t)i * 4) = h;
    if (lo) {
        ushort4 l;
        l.x = f32_to_bf16(v.x - bf16_to_f32(h.x));
        l.y = f32_to_bf16(v.y - bf16_to_f32(h.y));
        l.z = f32_to_bf16(v.z - bf16_to_f32(h.z));
        l.w = f32_to_bf16(v.w - bf16_to_f32(h.w));
        *reinterpret_cast<ushort4*>(lo + (size_t)i * 4) = l;
    }
}

// Split of the four 256x1024 freq/phase weights (one launch):
//   WfH/WfL = [WqfH;WkfH]/[lo]  (512x1024, split)
//   WpH     = [WqpH;WkpH]       (512x1024, hi only — phase needs no residual)
__global__ __launch_bounds__(256)
void split4_bf16(const float* __restrict__ Wqf, const float* __restrict__ Wkf,
                 const float* __restrict__ Wqp, const float* __restrict__ Wkp,
                 unsigned short* __restrict__ WfH, unsigned short* __restrict__ WfL,
                 unsigned short* __restrict__ WpH)
{
    const int i = blockIdx.x * 256 + threadIdx.x;   // 0..262143 (float4 units)
    const int sel = i >> 16, j = i & 65535;
    const float* W = (sel == 0) ? Wqf : (sel == 1) ? Wkf : (sel == 2) ? Wqp : Wkp;
    float4 v = *reinterpret_cast<const float4*>(W + (size_t)j * 4);
    ushort4 h;
    h.x = f32_to_bf16(v.x); h.y = f32_to_bf16(v.y);
    h.z = f32_to_bf16(v.z); h.w = f32_to_bf16(v.w);
    const size_t o = (size_t)(sel & 1) * 262144 + (size_t)j * 4;
    if (sel < 2) {
        *reinterpret_cast<ushort4*>(WfH + o) = h;
        ushort4 l;
        l.x = f32_to_bf16(v.x - bf16_to_f32(h.x));
        l.y = f32_to_bf16(v.y - bf16_to_f32(h.y));
        l.z = f32_to_bf16(v.z - bf16_to_f32(h.z));
        l.w = f32_to_bf16(v.w - bf16_to_f32(h.w));
        *reinterpret_cast<ushort4*>(WfL + o) = l;
    } else {
        *reinterpret_cast<ushort4*>(WpH + o) = h;
    }
}

// XCD-aware bijective remap: all bn-tiles of an A-panel share one XCD
// (hw xcd ~ linear_id % 8).  Requires nbm % 8 == 0.
__device__ __forceinline__ void xcd_tiles(int& tm, int& tn) {
    const int L = blockIdx.x + gridDim.x * blockIdx.y;
    const int nbn = gridDim.x;
    const int q3 = L >> 3;
    tn = q3 % nbn;
    tm = (L & 7) + 8 * (q3 / nbn);
}

// ---------------------------------------------------------------------------
// Fused freq+phase projection GEMM + sin + l2norm -> qn/kn bf16 [b,h,t,w].
// Tile 32(M:t) x 64(N:col), BK=64, 256 thr = 4 waves (2x2), wave owns 16x32.
// grid (8,128) = 1024 blocks (4/CU, 16 waves/CU) — occupancy is the lever;
// simple 2-barrier loop (hand vmcnt pipelines regressed, r8).
// K-segments: 0: xh*WfH, 1: xl*WfH, 2: xh*WfL  -> accF (split precision)
//             3: xh*WpH                        -> accP (plain bf16)
// LDS XOR-swizzle both-sides (rule #21).
// ---------------------------------------------------------------------------
__global__ __launch_bounds__(256)
void freq_gemm_norm(const unsigned short* __restrict__ xh,
                    const unsigned short* __restrict__ xl,
                    const unsigned short* __restrict__ WfH,
                    const unsigned short* __restrict__ WfL,
                    const unsigned short* __restrict__ WpH,
                    const float* __restrict__ bqf, const float* __restrict__ bkf,
                    const float* __restrict__ bqp, const float* __restrict__ bkp,
                    unsigned short* __restrict__ qn, unsigned short* __restrict__ kn)
{
    __shared__ __attribute__((aligned(16))) unsigned short Al[32 * 64];
    __shared__ __attribute__((aligned(16))) unsigned short Bl[64 * 64];

    int tm, tn;
    xcd_tiles(tm, tn);                 // nbn=8, nbm=128
    const int bm = tm * 32, bn = tn * 64;

    const int tid = threadIdx.x;
    const int w = tid >> 6, l = tid & 63;
    const int wr = w >> 1, wc = w & 1;
    const int lr = l & 15, lg = l >> 4;
    const int r8 = l >> 3;             // staging row in 8-row chunk
    const int c8 = l & 7;              // 16B slot in 128B row
    const int csw = (c8 ^ r8) << 3;    // inverse-swizzled global col

    f32x4 accF[2], accP[2];
#pragma unroll
    for (int j = 0; j < 2; j++)
#pragma unroll
        for (int r = 0; r < 4; r++) { accF[j][r] = 0.f; accP[j][r] = 0.f; }

    for (int t = 0; t < 64; ++t) {
        const int seg = t >> 4;
        const int kc = (t << 6) & 1023;
        const unsigned short* Aseg = (seg == 1) ? xl : xh;
        const unsigned short* Bseg = (seg <= 1) ? WfH : (seg == 2) ? WfL : WpH;

        // stage A rows [w*8, w*8+8), B rows [w*16, w*16+16); 16B/lane
        __builtin_amdgcn_global_load_lds(
            (glb_cvoid*)(Aseg + (size_t)(bm + w * 8 + r8) * 1024 + kc + csw),
            (lds_void*)(&Al[(w * 8) * 64]), 16, 0, 0);
#pragma unroll
        for (int i = 0; i < 2; i++)
            __builtin_amdgcn_global_load_lds(
                (glb_cvoid*)(Bseg + (size_t)(bn + w * 16 + i * 8 + r8) * 1024 + kc + csw),
                (lds_void*)(&Bl[(w * 16 + i * 8) * 64]), 16, 0, 0);
        __syncthreads();

        bf16x8 af[2], bfr[2][2];
#pragma unroll
        for (int kk = 0; kk < 2; kk++) {
            af[kk] = *reinterpret_cast<const bf16x8*>(
                &Al[(wr * 16 + lr) * 64 + (((kk * 4 + lg) ^ (lr & 7)) << 3)]);
#pragma unroll
            for (int j = 0; j < 2; j++)
                bfr[j][kk] = *reinterpret_cast<const bf16x8*>(
                    &Bl[(wc * 32 + j * 16 + lr) * 64 + (((kk * 4 + lg) ^ (lr & 7)) << 3)]);
        }
        if (seg < 3) {
#pragma unroll
            for (int kk = 0; kk < 2; kk++)
#pragma unroll
                for (int j = 0; j < 2; j++)
                    accF[j] = __builtin_amdgcn_mfma_f32_16x16x32_bf16(
                        af[kk], bfr[j][kk], accF[j], 0, 0, 0);
        } else {
#pragma unroll
            for (int kk = 0; kk < 2; kk++)
#pragma unroll
                for (int j = 0; j < 2; j++)
                    accP[j] = __builtin_amdgcn_mfma_f32_16x16x32_bf16(
                        af[kk], bfr[j][kk], accP[j], 0, 0, 0);
        }
        __syncthreads();
    }

    // epilogue: C/D col = lane&15, row = lg*4 + reg
#pragma unroll
    for (int j = 0; j < 2; j++) {
        const int col = bn + wc * 32 + j * 16 + lr;   // 0..511
        const bool isQ = col < 256;
        const int c = col & 255;
        const float bf = isQ ? bqf[c] : bkf[c];
        const float bp = isQ ? bqp[c] : bkp[c];
        unsigned short* dst = isQ ? qn : kn;
        const int h = c >> 4, ww = c & 15;
#pragma unroll
        for (int r = 0; r < 4; r++) {
            const int row = bm + wr * 16 + lg * 4 + r;
            const int b = row >> 10, t = row & 1023;
            const float f = accF[j][r] + bf;
            const float p = accP[j][r] + bp;
            const float s = __sinf(fmaf(f, (float)t, p));
            float n2 = s * s;
#pragma unroll
            for (int off = 8; off >= 1; off >>= 1)
                n2 += __shfl_xor(n2, off);
            const float val = s * 2.0f / fmaxf(sqrtf(n2), 1e-12f);
            dst[((size_t)(b * 16 + h) * 1024 + t) * 16 + ww] = f32_to_bf16(val);
        }
    }
}

// ---------------------------------------------------------------------------
// bf16 MFMA GEMM: C[m,n] = sum_k A[m,k] * B[n,k]   (A,B row-major, K contig)
// Tile 64(M) x 64(N), BK=64, 256 threads = 4 waves (2x2), wave owns 32x32.
// grid (16,64) = 1024 blocks (4/CU). Simple 2-barrier loop, XOR swizzle.
// MODE 1 (v):    K=1024, +bias, writes vtt[b,h,d,t] bf16 (d-major!).
// MODE 2 (out):  K=1024, +bias, writes f32 (d_out).
// ---------------------------------------------------------------------------
template <int MODE>
__global__ __launch_bounds__(256)
void mfma_gemm(const unsigned short* __restrict__ A0,
               const unsigned short* __restrict__ B0,
               const float* __restrict__ bias,
               float* __restrict__ outF, unsigned short* __restrict__ outH)
{
    __shared__ __attribute__((aligned(16))) unsigned short Al[64 * 64];
    __shared__ __attribute__((aligned(16))) unsigned short Bl[64 * 64];

    int tm, tn;
    xcd_tiles(tm, tn);                 // nbn=16, nbm=64
    const int bm = tm * 64, bn = tn * 64;

    const int tid = threadIdx.x;
    const int w = tid >> 6, l = tid & 63;
    const int wr = w >> 1, wc = w & 1;
    const int lr = l & 15, lg = l >> 4;
    const int r8 = l >> 3;
    const int c8 = l & 7;
    const int csw = (c8 ^ r8) << 3;

    f32x4 acc[2][2];
#pragma unroll
    for (int i = 0; i < 2; i++)
#pragma unroll
        for (int j = 0; j < 2; j++)
#pragma unroll
            for (int r = 0; r < 4; r++) acc[i][j][r] = 0.f;

    for (int t = 0; t < 16; ++t) {
        const int k0 = t << 6;
#pragma unroll
        for (int i = 0; i < 2; i++) {
            __builtin_amdgcn_global_load_lds(
                (glb_cvoid*)(A0 + (size_t)(bm + w * 16 + i * 8 + r8) * 1024 + k0 + csw),
                (lds_void*)(&Al[(w * 16 + i * 8) * 64]), 16, 0, 0);
            __builtin_amdgcn_global_load_lds(
                (glb_cvoid*)(B0 + (size_t)(bn + w * 16 + i * 8 + r8) * 1024 + k0 + csw),
                (lds_void*)(&Bl[(w * 16 + i * 8) * 64]), 16, 0, 0);
        }
        __syncthreads();

        bf16x8 af[2][2], bfr[2][2];
#pragma unroll
        for (int i = 0; i < 2; i++)
#pragma unroll
            for (int kk = 0; kk < 2; kk++) {
                af[i][kk] = *reinterpret_cast<const bf16x8*>(
                    &Al[(wr * 32 + i * 16 + lr) * 64 + (((kk * 4 + lg) ^ (lr & 7)) << 3)]);
                bfr[i][kk] = *reinterpret_cast<const bf16x8*>(
                    &Bl[(wc * 32 + i * 16 + lr) * 64 + (((kk * 4 + lg) ^ (lr & 7)) << 3)]);
            }
#pragma unroll
        for (int kk = 0; kk < 2; kk++)
#pragma unroll
            for (int i = 0; i < 2; i++)
#pragma unroll
                for (int j = 0; j < 2; j++)
                    acc[i][j] = __builtin_amdgcn_mfma_f32_16x16x32_bf16(
                        af[i][kk], bfr[j][kk], acc[i][j], 0, 0, 0);
        __syncthreads();
    }

#pragma unroll
    for (int i = 0; i < 2; i++) {
#pragma unroll
        for (int j = 0; j < 2; j++) {
#pragma unroll
            for (int r = 0; r < 4; r++) {
                const int row = bm + wr * 32 + i * 16 + lg * 4 + r;
                const int col = bn + wc * 32 + j * 16 + lr;
                float v = acc[i][j][r] + bias[col];
                if (MODE == 1) {
                    const int hh = col >> 6, d = col & 63;
                    const int b = row >> 10, t = row & 1023;
                    outH[(((size_t)(b * 16 + hh) * 64 + d) * 1024) + t] =
                        f32_to_bf16(v);
                } else {
                    outF[(size_t)row * 1024 + col] = v;
                }
            }
        }
    }
}

// ---------------------------------------------------------------------------
// MFMA causal linear attention, pair-balanced (unchanged from round 6/7).
// grid (8, bh=64), 512 thr = 8 independent waves (no LDS, no barriers).
// ---------------------------------------------------------------------------
__global__ __launch_bounds__(512)
void wave_attn_mfma(const unsigned short* __restrict__ qn,
                    const unsigned short* __restrict__ kn,
                    const unsigned short* __restrict__ vtt,
                    const float* __restrict__ iscale,
                    unsigned short* __restrict__ y)
{
    const int p = blockIdx.x, bh = blockIdx.y;
    const int h = bh & 15, b = bh >> 4;
    const int tid = threadIdx.x;
    const int wq = tid >> 6;          // wave 0..7
    const int l = tid & 63;
    const int lt = l & 15;
    const int gl = l >> 4;
    const int it = (wq < 4) ? p : (15 - p);
    const int t0w = it * 64 + (wq & 3) * 16;
    const float scale = iscale[h];
    const int tmine = t0w + lt;

    const bf16x8 zero8 = {0, 0, 0, 0, 0, 0, 0, 0};
    const f32x4 zf = {0.f, 0.f, 0.f, 0.f};
    const size_t kb = (size_t)bh * 1024;

    bf16x8 bq = zero8;
    if (gl < 2)
        bq = *reinterpret_cast<const bf16x8*>(&qn[(kb + t0w + lt) * 16 + gl * 8]);

    f32x4 o[4];
#pragma unroll
    for (int jd = 0; jd < 4; jd++) o[jd] = zf;

    const int addr0 = ((2 * (gl & 1)) * 16 + lt) * 4;
    const int addr1 = addr0 + 64;
    const bool hi = ((gl >> 1) & 1) != 0;

    bf16x8 akc[4], akn[4];
#pragma unroll
    for (int js = 0; js < 4; js++) {
        akc[js] = zero8;
        if (gl < 2)
            akc[js] = *reinterpret_cast<const bf16x8*>(
                &kn[(kb + js * 16 + lt) * 16 + gl * 8]);
    }

    for (int is = 0; is <= it; is++) {
        const int s0 = is * 64;

        if (is < it) {
#pragma unroll
            for (int js = 0; js < 4; js++) {
                akn[js] = zero8;
                if (gl < 2)
                    akn[js] = *reinterpret_cast<const bf16x8*>(
                        &kn[(kb + s0 + 64 + js * 16 + lt) * 16 + gl * 8]);
            }
        }
        bf16x8 bv[2][4];
#pragma unroll
        for (int ks = 0; ks < 2; ks++)
#pragma unroll
            for (int jd = 0; jd < 4; jd++)
                bv[ks][jd] = *reinterpret_cast<const bf16x8*>(
                    &vtt[((size_t)(bh * 64 + jd * 16 + lt)) * 1024 +
                         s0 + ks * 32 + gl * 8]);

        f32x4 st[4];
#pragma unroll
        for (int js = 0; js < 4; js++)
            st[js] = __builtin_amdgcn_mfma_f32_16x16x32_bf16(
                akc[js], bq, zf, 0, 0, 0);

        int pk[4][2];
#pragma unroll
        for (int js = 0; js < 4; js++) {
            float pp[4];
#pragma unroll
            for (int r = 0; r < 4; r++) {
                const int s = s0 + js * 16 + gl * 4 + r;
                const float xv = st[js][r] * scale;
                const float phi = (xv > 0.f) ? (xv + 1.0f) : __expf(xv);
                pp[r] = (s <= tmine) ? phi : 0.f;
            }
            asm("v_cvt_pk_bf16_f32 %0, %1, %2"
                : "=v"(pk[js][0]) : "v"(pp[0]), "v"(pp[1]));
            asm("v_cvt_pk_bf16_f32 %0, %1, %2"
                : "=v"(pk[js][1]) : "v"(pp[2]), "v"(pp[3]));
        }

        int rg[4][2][2];
#pragma unroll
        for (int js = 0; js < 4; js++)
#pragma unroll
            for (int sl = 0; sl < 2; sl++) {
                rg[js][sl][0] = __builtin_amdgcn_ds_bpermute(addr0, pk[js][sl]);
                rg[js][sl][1] = __builtin_amdgcn_ds_bpermute(addr1, pk[js][sl]);
            }

#pragma unroll
        for (int ks = 0; ks < 2; ks++) {
            i32x4 au;
#pragma unroll
            for (int c = 0; c < 2; c++)
#pragma unroll
                for (int sl = 0; sl < 2; sl++)
                    au[2 * c + sl] = hi ? rg[2 * ks + 1][sl][c]
                                        : rg[2 * ks][sl][c];
            const bf16x8 pa = __builtin_bit_cast(bf16x8, au);
#pragma unroll
            for (int jd = 0; jd < 4; jd++)
                o[jd] = __builtin_amdgcn_mfma_f32_16x16x32_bf16(
                    pa, bv[ks][jd], o[jd], 0, 0, 0);
        }

#pragma unroll
        for (int js = 0; js < 4; js++) akc[js] = akn[js];
    }

#pragma unroll
    for (int r = 0; r < 4; r++) {
        const int t = t0w + gl * 4 + r;
        const float inv = rsqrtf((float)(t + 1));
#pragma unroll
        for (int jd = 0; jd < 4; jd++) {
            const int d = jd * 16 + lt;
            y[((size_t)b * 1024 + t) * 1024 + h * 64 + d] =
                f32_to_bf16(o[jd][r] * inv);
        }
    }
}

// ---------------------------------------------------------------------------
extern "C" void kernel_launch(void* const* d_in, const int* in_sizes, int n_in,
                              void* d_out, int out_size, void* d_ws, size_t ws_size,
                              hipStream_t stream)
{
    const float* x   = (const float*)d_in[0];
    const float* Wqf = (const float*)d_in[1];
    const float* bqf = (const float*)d_in[2];
    const float* Wkf = (const float*)d_in[3];
    const float* bkf = (const float*)d_in[4];
    const float* Wqp = (const float*)d_in[5];
    const float* bqp = (const float*)d_in[6];
    const float* Wkp = (const float*)d_in[7];
    const float* bkp = (const float*)d_in[8];
    const float* Wv  = (const float*)d_in[9];
    const float* bv  = (const float*)d_in[10];
    const float* Wo  = (const float*)d_in[11];
    const float* bo  = (const float*)d_in[12];
    const float* isc = (const float*)d_in[13];
    float* out = (float*)d_out;

    // workspace plan (34 MB, zero live-range overlaps):
    //   [ 0, 8) ybf bf16 (attn out)
    //   [ 8,10) qn bf16   [10,12) kn bf16
    //   [12,13) WfH       [13,14) WfL       [14,15) WpH   (512x1024 each)
    //   [16,24) xh bf16   (dead after v GEMM)
    //   [24,32) xl bf16 -> vtt bf16 [b,h,d,t] after fused freq GEMM
    //   [32,34) WvH -> WoH (2 MB)
    char* ws = (char*)d_ws;
    unsigned short* ybf = (unsigned short*)(ws);
    unsigned short* qn  = (unsigned short*)(ws + ( 8u << 20));
    unsigned short* kn  = (unsigned short*)(ws + (10u << 20));
    unsigned short* WfH = (unsigned short*)(ws + (12u << 20));
    unsigned short* WfL = (unsigned short*)(ws + (13u << 20));
    unsigned short* WpH = (unsigned short*)(ws + (14u << 20));
    unsigned short* xh  = (unsigned short*)(ws + (16u << 20));
    unsigned short* xl  = (unsigned short*)(ws + (24u << 20));
    unsigned short* vtt = (unsigned short*)(ws + (24u << 20));
    unsigned short* WvH = (unsigned short*)(ws + (32u << 20));
    unsigned short* WoH = WvH;   // slot reuse after v GEMM

    // conversions
    split_bf16<<<4096, 256, 0, stream>>>(x, xh, xl, 1048576);
    split4_bf16<<<1024, 256, 0, stream>>>(Wqf, Wkf, Wqp, Wkp, WfH, WfL, WpH);

    // 1) fused freq(split K=3072) + phase(K=1024) GEMM + sin + l2norm
    freq_gemm_norm<<<dim3(8, 128), 256, 0, stream>>>(
        xh, xl, WfH, WfL, WpH, bqf, bkf, bqp, bkp, qn, kn);

    // 2) v projection -> vtt bf16 [b,h,d,t]  (overlays dead xl)
    split_bf16<<<1024, 256, 0, stream>>>(Wv, WvH, nullptr, 262144);
    mfma_gemm<1><<<dim3(16, 64), 256, 0, stream>>>(xh, WvH, bv, nullptr, vtt);

    // 3) MFMA causal linear attention (pair-balanced) -> ybf bf16
    wave_attn_mfma<<<dim3(8, 64), 512, 0, stream>>>(qn, kn, vtt, isc, ybf);

    // 4) output projection -> d_out f32
    split_bf16<<<1024, 256, 0, stream>>>(Wo, WoH, nullptr, 262144);
    mfma_gemm<2><<<dim3(16, 64), 256, 0, stream>>>(ybf, WoH, bo, out, nullptr);
}